// Round 1
// baseline (27456.769 us; speedup 1.0000x reference)
//
#include <hip/hip_runtime.h>
#include <math.h>

#define NEG_INF (-__builtin_inf())

constexpr int N = 2048;
constexpr int NCHUNK = 32;
constexpr int RPC = N / NCHUNK;   // 64 rows per chunk

// ---------------- column stats (BN1: stats over rows, per column) ----------------
template<typename T>
__global__ __launch_bounds__(256) void colstats_partial(const T* __restrict__ X, double* __restrict__ part){
  int col = blockIdx.x * 256 + threadIdx.x;
  int r0  = blockIdx.y * RPC;
  double s = 0.0, q = 0.0;
  for (int r = r0; r < r0 + RPC; ++r){
    double v = (double)X[(size_t)r * N + col];
    s += v; q += v * v;
  }
  size_t o = (size_t)blockIdx.y * N + col;
  part[o*2+0] = s; part[o*2+1] = q;
}

__global__ __launch_bounds__(256) void colstats_final(const double* __restrict__ part,
    const float* __restrict__ g, const float* __restrict__ be,
    double* __restrict__ A, double* __restrict__ C){
  int col = blockIdx.x * 256 + threadIdx.x;
  double s = 0.0, q = 0.0;
  for (int k = 0; k < NCHUNK; ++k){
    size_t o = (size_t)k * N + col;
    s += part[o*2+0]; q += part[o*2+1];
  }
  double mu  = s / (double)N;
  double var = q / (double)N - mu * mu;
  double inv = 1.0 / sqrt(var + 1e-5);
  double a = (double)g[col] * inv;
  A[col] = a;
  C[col] = (double)be[col] - mu * a;
}

// ---------------- row stats (BN2: stats per row) ----------------
template<typename T>
__global__ __launch_bounds__(256) void rowstats(const T* __restrict__ Z,
    const float* __restrict__ g, const float* __restrict__ be,
    double* __restrict__ A, double* __restrict__ C){
  __shared__ double s1[256], s2[256];
  int r = blockIdx.x, tx = threadIdx.x;
  double s = 0.0, q = 0.0;
  for (int j = tx; j < N; j += 256){
    double v = (double)Z[(size_t)r * N + j];
    s += v; q += v * v;
  }
  s1[tx] = s; s2[tx] = q; __syncthreads();
  for (int st = 128; st; st >>= 1){
    if (tx < st){ s1[tx] += s1[tx + st]; s2[tx] += s2[tx + st]; }
    __syncthreads();
  }
  if (tx == 0){
    double mu  = s1[0] / (double)N;
    double var = s2[0] / (double)N - mu * mu;
    double inv = 1.0 / sqrt(var + 1e-5);
    double a = (double)g[r] * inv;
    A[r] = a;
    C[r] = (double)be[r] - mu * a;
  }
}

// ---------------- fused BN + ReLU ----------------
template<typename Tin, typename Tout>
__global__ __launch_bounds__(256) void bnrelu_col(const Tin* __restrict__ X,
    const double* __restrict__ A, const double* __restrict__ C, Tout* __restrict__ O){
  int i = blockIdx.x;
  for (int j = threadIdx.x; j < N; j += 256){
    double v = fma((double)X[(size_t)i * N + j], A[j], C[j]);
    O[(size_t)i * N + j] = (Tout)(v > 0.0 ? v : 0.0);
  }
}

template<typename Tin, typename Tout>
__global__ __launch_bounds__(256) void bnrelu_row(const Tin* __restrict__ Z,
    const double* __restrict__ A, const double* __restrict__ C, Tout* __restrict__ O){
  int i = blockIdx.x;
  double a = A[i], c = C[i];
  for (int j = threadIdx.x; j < N; j += 256){
    double v = fma((double)Z[(size_t)i * N + j], a, c);
    O[(size_t)i * N + j] = (Tout)(v > 0.0 ? v : 0.0);
  }
}

// ---------------- f64-accumulate tiled GEMM ----------------
// O[i,j] = sum_k A[i,k] * (BT ? B[j,k] : B[k,j]) + (BIAS_ROW ? bias[i] : bias[j])
template<typename TA, typename TB, typename TO, bool BT, bool BIAS_ROW>
__global__ __launch_bounds__(256) void gemm64(const TA* __restrict__ A, const TB* __restrict__ B,
    const float* __restrict__ bias, TO* __restrict__ O){
  __shared__ double sA[16][68];
  __shared__ double sB[16][68];
  const int tid = threadIdx.x;
  const int tx = tid & 15, ty = tid >> 4;
  const int i0 = blockIdx.y * 64, j0 = blockIdx.x * 64;
  double acc[4][4] = {};
  for (int k0 = 0; k0 < N; k0 += 16){
    { // A tile: 64 (M) x 16 (K)
      int r = tid >> 2, c4 = (tid & 3) * 4;
      const TA* p = A + (size_t)(i0 + r) * N + k0 + c4;
      double v0 = (double)p[0], v1 = (double)p[1], v2 = (double)p[2], v3 = (double)p[3];
      sA[c4+0][r] = v0; sA[c4+1][r] = v1; sA[c4+2][r] = v2; sA[c4+3][r] = v3;
    }
    if (!BT){ // B tile: 16 (K) x 64 (Ncol)
      int k = tid >> 4, j4 = (tid & 15) * 4;
      const TB* p = B + (size_t)(k0 + k) * N + j0 + j4;
      sB[k][j4+0] = (double)p[0]; sB[k][j4+1] = (double)p[1];
      sB[k][j4+2] = (double)p[2]; sB[k][j4+3] = (double)p[3];
    } else {  // B tile from B[j, k]
      int j = tid >> 2, c4 = (tid & 3) * 4;
      const TB* p = B + (size_t)(j0 + j) * N + k0 + c4;
      double v0 = (double)p[0], v1 = (double)p[1], v2 = (double)p[2], v3 = (double)p[3];
      sB[c4+0][j] = v0; sB[c4+1][j] = v1; sB[c4+2][j] = v2; sB[c4+3][j] = v3;
    }
    __syncthreads();
    #pragma unroll
    for (int kk = 0; kk < 16; ++kk){
      double a_[4], b_[4];
      #pragma unroll
      for (int q = 0; q < 4; ++q){ a_[q] = sA[kk][ty*4+q]; b_[q] = sB[kk][tx*4+q]; }
      #pragma unroll
      for (int mi = 0; mi < 4; ++mi)
        #pragma unroll
        for (int ni = 0; ni < 4; ++ni)
          acc[mi][ni] = fma(a_[mi], b_[ni], acc[mi][ni]);
    }
    __syncthreads();
  }
  #pragma unroll
  for (int mi = 0; mi < 4; ++mi){
    int i = i0 + ty*4 + mi;
    #pragma unroll
    for (int ni = 0; ni < 4; ++ni){
      int j = j0 + tx*4 + ni;
      double bv = BIAS_ROW ? (double)bias[i] : (double)bias[j];
      O[(size_t)i * N + j] = (TO)(acc[mi][ni] + bv);
    }
  }
}

// ---------------- per-row max init ----------------
template<typename T>
__global__ __launch_bounds__(256) void rowmax_init(const T* __restrict__ O,
    double* __restrict__ rowVal, unsigned* __restrict__ rowCol){
  __shared__ double sv[256];
  __shared__ unsigned sc[256];
  int r = blockIdx.x, tx = threadIdx.x;
  double bv = NEG_INF; unsigned bc = 0;
  for (int c = tx; c < N; c += 256){
    double v = (double)O[(size_t)r * N + c];
    if (v > bv){ bv = v; bc = (unsigned)c; }   // increasing c: strict > keeps smallest col
  }
  sv[tx] = bv; sc[tx] = bc; __syncthreads();
  for (int st = 128; st; st >>= 1){
    if (tx < st){
      if (sv[tx+st] > sv[tx] || (sv[tx+st] == sv[tx] && sc[tx+st] < sc[tx])){
        sv[tx] = sv[tx+st]; sc[tx] = sc[tx+st];
      }
    }
    __syncthreads();
  }
  if (tx == 0){ rowVal[r] = sv[0]; rowCol[r] = sc[0]; }
}

// ---------------- serial greedy argmax with row/col elimination ----------------
// Maintains per-row (max value, argmax col); invalidated rows (stored col just
// eliminated) are rescanned one wave per row. Tie-break replicates flat argmax:
// max value, then min row, then min col.
template<typename T>
__global__ __launch_bounds__(1024) void greedy(const T* __restrict__ O,
    const double* __restrict__ rowVal_g, const unsigned* __restrict__ rowCol_g,
    unsigned* __restrict__ rowStep_g, unsigned* __restrict__ colStep_g){
  __shared__ double rv[N];
  __shared__ unsigned rc[N];
  __shared__ unsigned long long colMask[N/64];
  __shared__ double redV[16];
  __shared__ unsigned redR[16], redC[16];
  __shared__ unsigned selJ, rescanCnt;
  __shared__ unsigned rescanList[N];
  const int tid = threadIdx.x;
  const int lane = tid & 63, wave = tid >> 6;

  for (int i = tid; i < N; i += 1024){ rv[i] = rowVal_g[i]; rc[i] = rowCol_g[i]; }
  for (int i = tid; i < N/64; i += 1024) colMask[i] = ~0ull;
  __syncthreads();

  for (int t = 0; t < N; ++t){
    // --- 1. global argmax over per-row maxima ---
    double v = rv[tid]; unsigned r = (unsigned)tid, c = rc[tid];
    {
      double v1 = rv[tid + 1024];
      if (v1 > v){ v = v1; r = (unsigned)(tid + 1024); c = rc[tid + 1024]; } // tie -> smaller row
    }
    #pragma unroll
    for (int off = 32; off; off >>= 1){
      double ov = __shfl_xor(v, off);
      unsigned orr = __shfl_xor(r, off);
      unsigned oc  = __shfl_xor(c, off);
      if (ov > v || (ov == v && (orr < r || (orr == r && oc < c)))){ v = ov; r = orr; c = oc; }
    }
    if (lane == 0){ redV[wave] = v; redR[wave] = r; redC[wave] = c; }
    __syncthreads();
    if (tid == 0){
      double bv = redV[0]; unsigned br = redR[0], bc = redC[0];
      for (int w = 1; w < 16; ++w){
        if (redV[w] > bv || (redV[w] == bv && (redR[w] < br || (redR[w] == br && redC[w] < bc)))){
          bv = redV[w]; br = redR[w]; bc = redC[w];
        }
      }
      selJ = bc;
      rowStep_g[br] = (unsigned)t;
      colStep_g[bc] = (unsigned)t;
      rv[br] = NEG_INF;
      colMask[bc >> 6] &= ~(1ull << (bc & 63));
      rescanCnt = 0;
    }
    __syncthreads();
    // --- 2. collect rows whose stored argmax column was eliminated ---
    unsigned j = selJ;
    for (int i = tid; i < N; i += 1024){
      if (rc[i] == j && rv[i] != NEG_INF){
        unsigned idx = atomicAdd(&rescanCnt, 1u);
        rescanList[idx] = (unsigned)i;
      }
    }
    __syncthreads();
    // --- 3. rescan stale rows, one wave per row ---
    for (unsigned idx = (unsigned)wave; idx < rescanCnt; idx += 16){
      unsigned rr = rescanList[idx];
      double bv = NEG_INF; unsigned bc = 0;
      for (int cc = lane; cc < N; cc += 64){
        if ((colMask[cc >> 6] >> (cc & 63)) & 1ull){
          double x = (double)O[(size_t)rr * N + cc];
          if (x > bv){ bv = x; bc = (unsigned)cc; }
        }
      }
      #pragma unroll
      for (int off = 32; off; off >>= 1){
        double ov = __shfl_xor(bv, off);
        unsigned oc = __shfl_xor(bc, off);
        if (ov > bv || (ov == bv && oc < bc)){ bv = ov; bc = oc; }
      }
      if (lane == 0){ rv[rr] = bv; rc[rr] = bc; }
    }
    __syncthreads();
  }
}

// ---------------- masked row softmax: mask[r,c] = (rowStep[r] > colStep[c]) ----------------
template<typename T>
__global__ __launch_bounds__(256) void masked_softmax(const T* __restrict__ O,
    const unsigned* __restrict__ rowStep, const unsigned* __restrict__ colStep,
    float* __restrict__ out){
  __shared__ double vals[N];
  __shared__ double red[256];
  int r = blockIdx.x, tx = threadIdx.x;
  unsigned s = rowStep[r];
  double mx = NEG_INF;
  for (int c = tx; c < N; c += 256){
    double v = (colStep[c] >= s) ? (double)O[(size_t)r * N + c] : NEG_INF;
    vals[c] = v;
    if (v > mx) mx = v;
  }
  red[tx] = mx; __syncthreads();
  for (int st = 128; st; st >>= 1){
    if (tx < st) red[tx] = fmax(red[tx], red[tx + st]);
    __syncthreads();
  }
  mx = red[0]; __syncthreads();
  double sm = 0.0;
  for (int c = tx; c < N; c += 256){
    double v = vals[c];
    if (v != NEG_INF) sm += exp(v - mx);
  }
  red[tx] = sm; __syncthreads();
  for (int st = 128; st; st >>= 1){
    if (tx < st) red[tx] += red[tx + st];
    __syncthreads();
  }
  double inv = 1.0 / red[0];
  for (int c = tx; c < N; c += 256){
    double v = vals[c];
    out[(size_t)r * N + c] = (v != NEG_INF) ? (float)(exp(v - mx) * inv) : 0.0f;
  }
}

// ---------------- pipeline ----------------
template<typename T>
static void run_pipeline(const float* x, const float* g1, const float* be1,
                         const float* W1, const float* bi1,
                         const float* g2, const float* be2,
                         const float* W2, const float* bi2,
                         float* out, T* buf0, T* buf1,
                         double* part, double* stA, double* stC,
                         double* rowVal, unsigned* rowCol,
                         unsigned* rowStep, unsigned* colStep,
                         hipStream_t s){
  dim3 gs(N/256, NCHUNK);
  dim3 gg(N/64, N/64);
  // ---- s-block 0 ----
  colstats_partial<float><<<gs,256,0,s>>>(x, part);
  colstats_final<<<N/256,256,0,s>>>(part, g1, be1, stA, stC);
  bnrelu_col<float,T><<<N,256,0,s>>>(x, stA, stC, buf0);
  gemm64<float,T,T,false,true><<<gg,256,0,s>>>(W1, buf0, bi1, buf1);            // Z
  rowstats<T><<<N,256,0,s>>>(buf1, g2, be2, stA, stC);
  bnrelu_row<T,T><<<N,256,0,s>>>(buf1, stA, stC, buf0);                          // C
  gemm64<T,float,T,true,false><<<gg,256,0,s>>>(buf0, W2, bi2, buf1);             // O1
  // ---- s-block 1 ----
  colstats_partial<T><<<gs,256,0,s>>>(buf1, part);
  colstats_final<<<N/256,256,0,s>>>(part, g1+N, be1+N, stA, stC);
  bnrelu_col<T,T><<<N,256,0,s>>>(buf1, stA, stC, buf0);
  gemm64<float,T,T,false,true><<<gg,256,0,s>>>(W1+(size_t)N*N, buf0, bi1+N, buf1); // Z'
  rowstats<T><<<N,256,0,s>>>(buf1, g2+N, be2+N, stA, stC);
  bnrelu_row<T,T><<<N,256,0,s>>>(buf1, stA, stC, buf0);                          // C'
  gemm64<T,float,T,true,false><<<gg,256,0,s>>>(buf0, W2+(size_t)N*N, bi2+N, buf1); // O2
  // ---- greedy mask + softmax ----
  rowmax_init<T><<<N,256,0,s>>>(buf1, rowVal, rowCol);
  greedy<T><<<1,1024,0,s>>>(buf1, rowVal, rowCol, rowStep, colStep);
  masked_softmax<T><<<N,256,0,s>>>(buf1, rowStep, colStep, out);
}

extern "C" void kernel_launch(void* const* d_in, const int* in_sizes, int n_in,
                              void* d_out, int out_size, void* d_ws, size_t ws_size,
                              hipStream_t stream){
  if (n_in < 9) return;
  const float* x   = (const float*)d_in[0];
  const float* g1  = (const float*)d_in[1];
  const float* be1 = (const float*)d_in[2];
  const float* W1  = (const float*)d_in[3];
  const float* bi1 = (const float*)d_in[4];
  const float* g2  = (const float*)d_in[5];
  const float* be2 = (const float*)d_in[6];
  const float* W2  = (const float*)d_in[7];
  const float* bi2 = (const float*)d_in[8];
  float* out = (float*)d_out;

  char* base = (char*)d_ws;
  size_t off = 0;
  auto carve = [&](size_t bytes)->void*{
    void* q = base + off;
    off = (off + bytes + 255) & ~(size_t)255;
    return q;
  };
  double*   part    = (double*)carve((size_t)NCHUNK * N * 2 * sizeof(double));
  double*   stA     = (double*)carve(N * sizeof(double));
  double*   stC     = (double*)carve(N * sizeof(double));
  double*   rowVal  = (double*)carve(N * sizeof(double));
  unsigned* rowCol  = (unsigned*)carve(N * sizeof(unsigned));
  unsigned* rowStep = (unsigned*)carve(N * sizeof(unsigned));
  unsigned* colStep = (unsigned*)carve(N * sizeof(unsigned));
  size_t smallEnd = off;

  const size_t matD = (size_t)N * N * sizeof(double);
  const size_t matF = (size_t)N * N * sizeof(float);
  size_t needD  = smallEnd + 2 * (matD + 256);
  size_t needF  = smallEnd + 2 * (matF + 256);
  size_t needF1 = smallEnd + 1 * (matF + 256);

  if (ws_size >= needD){
    double* b0 = (double*)carve(matD);
    double* b1 = (double*)carve(matD);
    run_pipeline<double>(x,g1,be1,W1,bi1,g2,be2,W2,bi2, out, b0, b1,
                         part, stA, stC, rowVal, rowCol, rowStep, colStep, stream);
  } else if (ws_size >= needF){
    float* b0 = (float*)carve(matF);
    float* b1 = (float*)carve(matF);
    run_pipeline<float>(x,g1,be1,W1,bi1,g2,be2,W2,bi2, out, b0, b1,
                        part, stA, stC, rowVal, rowCol, rowStep, colStep, stream);
  } else if (ws_size >= needF1){
    float* b0 = (float*)carve(matF);
    float* b1 = out;   // use d_out as second buffer; softmax stages rows in LDS, in-place safe
    run_pipeline<float>(x,g1,be1,W1,bi1,g2,be2,W2,bi2, out, b0, b1,
                        part, stA, stC, rowVal, rowCol, rowStep, colStep, stream);
  }
}

// Round 2
// 11903.917 us; speedup vs baseline: 2.3065x; 2.3065x over previous
//
#include <hip/hip_runtime.h>
#include <math.h>

#define NEG_INF (-__builtin_inf())

typedef unsigned long long u64;

constexpr int N = 2048;
constexpr int NCHUNK = 32;
constexpr int RPC = N / NCHUNK;   // 64 rows per chunk

// ---------------- monotonic order-preserving keys ----------------
template<typename T> struct Key;
template<> struct Key<float>{
  static __device__ inline u64 pack(float x){
    unsigned u = __float_as_uint(x);
    u = (u & 0x80000000u) ? ~u : (u | 0x80000000u);
    return (u64)u;
  }
};
template<> struct Key<double>{
  static __device__ inline u64 pack(double x){
    u64 u = (u64)__double_as_longlong(x);
    return (u >> 63) ? ~u : (u | 0x8000000000000000ull);
  }
};

// comparator: bigger key wins; tie -> smaller rc (rc = row<<11|col or just col)
__device__ inline bool kbetter(u64 k, unsigned rc, u64 bk, unsigned brc){
  return (k > bk) || (k == bk && rc < brc);
}

// ---------------- column stats (BN1: stats over rows, per column) ----------------
template<typename T>
__global__ __launch_bounds__(256) void colstats_partial(const T* __restrict__ X, double* __restrict__ part){
  int col = blockIdx.x * 256 + threadIdx.x;
  int r0  = blockIdx.y * RPC;
  double s = 0.0, q = 0.0;
  for (int r = r0; r < r0 + RPC; ++r){
    double v = (double)X[(size_t)r * N + col];
    s += v; q += v * v;
  }
  size_t o = (size_t)blockIdx.y * N + col;
  part[o*2+0] = s; part[o*2+1] = q;
}

__global__ __launch_bounds__(256) void colstats_final(const double* __restrict__ part,
    const float* __restrict__ g, const float* __restrict__ be,
    double* __restrict__ A, double* __restrict__ C){
  int col = blockIdx.x * 256 + threadIdx.x;
  double s = 0.0, q = 0.0;
  for (int k = 0; k < NCHUNK; ++k){
    size_t o = (size_t)k * N + col;
    s += part[o*2+0]; q += part[o*2+1];
  }
  double mu  = s / (double)N;
  double var = q / (double)N - mu * mu;
  double inv = 1.0 / sqrt(var + 1e-5);
  double a = (double)g[col] * inv;
  A[col] = a;
  C[col] = (double)be[col] - mu * a;
}

// ---------------- row stats (BN2: stats per row) ----------------
template<typename T>
__global__ __launch_bounds__(256) void rowstats(const T* __restrict__ Z,
    const float* __restrict__ g, const float* __restrict__ be,
    double* __restrict__ A, double* __restrict__ C){
  __shared__ double s1[256], s2[256];
  int r = blockIdx.x, tx = threadIdx.x;
  double s = 0.0, q = 0.0;
  for (int j = tx; j < N; j += 256){
    double v = (double)Z[(size_t)r * N + j];
    s += v; q += v * v;
  }
  s1[tx] = s; s2[tx] = q; __syncthreads();
  for (int st = 128; st; st >>= 1){
    if (tx < st){ s1[tx] += s1[tx + st]; s2[tx] += s2[tx + st]; }
    __syncthreads();
  }
  if (tx == 0){
    double mu  = s1[0] / (double)N;
    double var = s2[0] / (double)N - mu * mu;
    double inv = 1.0 / sqrt(var + 1e-5);
    double a = (double)g[r] * inv;
    A[r] = a;
    C[r] = (double)be[r] - mu * a;
  }
}

// ---------------- fused BN + ReLU ----------------
template<typename Tin, typename Tout>
__global__ __launch_bounds__(256) void bnrelu_col(const Tin* __restrict__ X,
    const double* __restrict__ A, const double* __restrict__ C, Tout* __restrict__ O){
  int i = blockIdx.x;
  for (int j = threadIdx.x; j < N; j += 256){
    double v = fma((double)X[(size_t)i * N + j], A[j], C[j]);
    O[(size_t)i * N + j] = (Tout)(v > 0.0 ? v : 0.0);
  }
}

template<typename Tin, typename Tout>
__global__ __launch_bounds__(256) void bnrelu_row(const Tin* __restrict__ Z,
    const double* __restrict__ A, const double* __restrict__ C, Tout* __restrict__ O){
  int i = blockIdx.x;
  double a = A[i], c = C[i];
  for (int j = threadIdx.x; j < N; j += 256){
    double v = fma((double)Z[(size_t)i * N + j], a, c);
    O[(size_t)i * N + j] = (Tout)(v > 0.0 ? v : 0.0);
  }
}

// ---------------- f64-accumulate tiled GEMM ----------------
// O[i,j] = sum_k A[i,k] * (BT ? B[j,k] : B[k,j]) + (BIAS_ROW ? bias[i] : bias[j])
template<typename TA, typename TB, typename TO, bool BT, bool BIAS_ROW>
__global__ __launch_bounds__(256) void gemm64(const TA* __restrict__ A, const TB* __restrict__ B,
    const float* __restrict__ bias, TO* __restrict__ O){
  __shared__ double sA[16][68];
  __shared__ double sB[16][68];
  const int tid = threadIdx.x;
  const int tx = tid & 15, ty = tid >> 4;
  const int i0 = blockIdx.y * 64, j0 = blockIdx.x * 64;
  double acc[4][4] = {};
  for (int k0 = 0; k0 < N; k0 += 16){
    { // A tile: 64 (M) x 16 (K)
      int r = tid >> 2, c4 = (tid & 3) * 4;
      const TA* p = A + (size_t)(i0 + r) * N + k0 + c4;
      double v0 = (double)p[0], v1 = (double)p[1], v2 = (double)p[2], v3 = (double)p[3];
      sA[c4+0][r] = v0; sA[c4+1][r] = v1; sA[c4+2][r] = v2; sA[c4+3][r] = v3;
    }
    if (!BT){ // B tile: 16 (K) x 64 (Ncol)
      int k = tid >> 4, j4 = (tid & 15) * 4;
      const TB* p = B + (size_t)(k0 + k) * N + j0 + j4;
      sB[k][j4+0] = (double)p[0]; sB[k][j4+1] = (double)p[1];
      sB[k][j4+2] = (double)p[2]; sB[k][j4+3] = (double)p[3];
    } else {  // B tile from B[j, k]
      int j = tid >> 2, c4 = (tid & 3) * 4;
      const TB* p = B + (size_t)(j0 + j) * N + k0 + c4;
      double v0 = (double)p[0], v1 = (double)p[1], v2 = (double)p[2], v3 = (double)p[3];
      sB[c4+0][j] = v0; sB[c4+1][j] = v1; sB[c4+2][j] = v2; sB[c4+3][j] = v3;
    }
    __syncthreads();
    #pragma unroll
    for (int kk = 0; kk < 16; ++kk){
      double a_[4], b_[4];
      #pragma unroll
      for (int q = 0; q < 4; ++q){ a_[q] = sA[kk][ty*4+q]; b_[q] = sB[kk][tx*4+q]; }
      #pragma unroll
      for (int mi = 0; mi < 4; ++mi)
        #pragma unroll
        for (int ni = 0; ni < 4; ++ni)
          acc[mi][ni] = fma(a_[mi], b_[ni], acc[mi][ni]);
    }
    __syncthreads();
  }
  #pragma unroll
  for (int mi = 0; mi < 4; ++mi){
    int i = i0 + ty*4 + mi;
    #pragma unroll
    for (int ni = 0; ni < 4; ++ni){
      int j = j0 + tx*4 + ni;
      double bv = BIAS_ROW ? (double)bias[i] : (double)bias[j];
      O[(size_t)i * N + j] = (TO)(acc[mi][ni] + bv);
    }
  }
}

// ---------------- per-row max init (packed keys) ----------------
template<typename T>
__global__ __launch_bounds__(256) void rowmax_init2(const T* __restrict__ O,
    u64* __restrict__ rvK_g, unsigned* __restrict__ rvRC_g){
  __shared__ u64 sk[256];
  __shared__ unsigned sc[256];
  int r = blockIdx.x, tx = threadIdx.x;
  u64 bk = 0; unsigned bc = 0xFFFFFFFFu;
  for (int c = tx; c < N; c += 256){
    u64 k = Key<T>::pack(O[(size_t)r * N + c]);
    if (k > bk){ bk = k; bc = (unsigned)c; }   // ascending c: strict > keeps smallest col
  }
  sk[tx] = bk; sc[tx] = bc; __syncthreads();
  for (int st = 128; st; st >>= 1){
    if (tx < st){
      if (kbetter(sk[tx+st], sc[tx+st], sk[tx], sc[tx])){ sk[tx] = sk[tx+st]; sc[tx] = sc[tx+st]; }
    }
    __syncthreads();
  }
  if (tx == 0){ rvK_g[r] = sk[0]; rvRC_g[r] = ((unsigned)r << 11) | sc[0]; }
}

// ---------------- serial greedy argmax with row/col elimination (v2) ----------------
// Per-row cached (key, rc). Per step: parallel 2048-way argmax on packed keys
// (exact np tie-break: max val, min row, min col), commit, then branch-free
// unrolled rescan of rows whose cached argmax column was just eliminated.
template<typename T>
__global__ __launch_bounds__(1024) void greedy2(const T* __restrict__ O,
    const u64* __restrict__ rvK_g, const unsigned* __restrict__ rvRC_g,
    unsigned* __restrict__ rowStep_g, unsigned* __restrict__ colStep_g){
  __shared__ u64 rvK[N];
  __shared__ unsigned rvRC[N];
  __shared__ u64 colMask[N/64];
  __shared__ u64 wK[16];
  __shared__ unsigned wRC[16];
  __shared__ unsigned sSelC, sCnt;
  __shared__ unsigned sList[N];
  const int tid  = threadIdx.x;
  const int lane = tid & 63, wave = tid >> 6;

  for (int i = tid; i < N; i += 1024){ rvK[i] = rvK_g[i]; rvRC[i] = rvRC_g[i]; }
  if (tid < N/64) colMask[tid] = ~0ull;
  __syncthreads();

  for (int t = 0; t < N; ++t){
    // --- 1. global argmax over per-row cached maxima ---
    u64 k = rvK[tid]; unsigned rc = rvRC[tid];
    {
      u64 k1 = rvK[tid + 1024]; unsigned rc1 = rvRC[tid + 1024];
      if (kbetter(k1, rc1, k, rc)){ k = k1; rc = rc1; }
    }
    #pragma unroll
    for (int off = 32; off; off >>= 1){
      u64 ok = __shfl_xor(k, off);
      unsigned orc = __shfl_xor(rc, off);
      if (kbetter(ok, orc, k, rc)){ k = ok; rc = orc; }
    }
    if (lane == 0){ wK[wave] = k; wRC[wave] = rc; }
    __syncthreads();
    // --- 2. cross-wave reduce (wave 0, lanes 0..15) + commit ---
    if (wave == 0){
      u64 ck = (lane < 16) ? wK[lane] : 0;
      unsigned crc = (lane < 16) ? wRC[lane] : 0xFFFFFFFFu;
      #pragma unroll
      for (int off = 8; off; off >>= 1){
        u64 ok = __shfl_xor(ck, off);
        unsigned orc = __shfl_xor(crc, off);
        if (kbetter(ok, orc, ck, crc)){ ck = ok; crc = orc; }
      }
      if (lane == 0){
        unsigned selR = crc >> 11, selC = crc & 2047u;
        rowStep_g[selR] = (unsigned)t;
        colStep_g[selC] = (unsigned)t;
        rvK[selR] = 0; rvRC[selR] = 0xFFFFFFFFu;
        colMask[selC >> 6] &= ~(1ull << (selC & 63));
        sSelC = selC; sCnt = 0;
      }
    }
    __syncthreads();
    // --- 3. detect stale rows (cached argmax col just eliminated) ---
    const unsigned selC = sSelC;
    if (rvK[tid] != 0 && (rvRC[tid] & 2047u) == selC)
      sList[atomicAdd(&sCnt, 1u)] = (unsigned)tid;
    if (rvK[tid + 1024] != 0 && (rvRC[tid + 1024] & 2047u) == selC)
      sList[atomicAdd(&sCnt, 1u)] = (unsigned)(tid + 1024);
    __syncthreads();
    // --- 4. branch-free unrolled rescan, one wave per stale row ---
    const unsigned cnt = sCnt;
    for (unsigned q = (unsigned)wave; q < cnt; q += 16){
      unsigned rr = sList[q];
      const T* __restrict__ row = O + (size_t)rr * N;
      u64 bk = 0; unsigned bc = 0xFFFFFFFFu;
      #pragma unroll
      for (int it = 0; it < N/64; ++it){
        int cc = lane + it * 64;
        T x = row[cc];                        // unconditional: loads batch up
        u64 kk = Key<T>::pack(x);
        u64 m = colMask[it];                  // wave-uniform broadcast
        if (!((m >> lane) & 1ull)) kk = 0;
        if (kbetter(kk, (unsigned)cc, bk, bc)){ bk = kk; bc = (unsigned)cc; }
      }
      #pragma unroll
      for (int off = 32; off; off >>= 1){
        u64 ok = __shfl_xor(bk, off);
        unsigned oc = __shfl_xor(bc, off);
        if (kbetter(ok, oc, bk, bc)){ bk = ok; bc = oc; }
      }
      if (lane == 0){ rvK[rr] = bk; rvRC[rr] = (rr << 11) | (bc & 2047u); }
    }
    __syncthreads();
  }
}

// ---------------- masked row softmax: mask[r,c] = (rowStep[r] > colStep[c]) ----------------
template<typename T>
__global__ __launch_bounds__(256) void masked_softmax(const T* __restrict__ O,
    const unsigned* __restrict__ rowStep, const unsigned* __restrict__ colStep,
    float* __restrict__ out){
  __shared__ double vals[N];
  __shared__ double red[256];
  int r = blockIdx.x, tx = threadIdx.x;
  unsigned s = rowStep[r];
  double mx = NEG_INF;
  for (int c = tx; c < N; c += 256){
    double v = (colStep[c] >= s) ? (double)O[(size_t)r * N + c] : NEG_INF;
    vals[c] = v;
    if (v > mx) mx = v;
  }
  red[tx] = mx; __syncthreads();
  for (int st = 128; st; st >>= 1){
    if (tx < st) red[tx] = fmax(red[tx], red[tx + st]);
    __syncthreads();
  }
  mx = red[0]; __syncthreads();
  double sm = 0.0;
  for (int c = tx; c < N; c += 256){
    double v = vals[c];
    if (v != NEG_INF) sm += exp(v - mx);
  }
  red[tx] = sm; __syncthreads();
  for (int st = 128; st; st >>= 1){
    if (tx < st) red[tx] += red[tx + st];
    __syncthreads();
  }
  double inv = 1.0 / red[0];
  for (int c = tx; c < N; c += 256){
    double v = vals[c];
    out[(size_t)r * N + c] = (v != NEG_INF) ? (float)(exp(v - mx) * inv) : 0.0f;
  }
}

// ---------------- pipeline ----------------
template<typename T>
static void run_pipeline(const float* x, const float* g1, const float* be1,
                         const float* W1, const float* bi1,
                         const float* g2, const float* be2,
                         const float* W2, const float* bi2,
                         float* out, T* buf0, T* buf1,
                         double* part, double* stA, double* stC,
                         u64* rvK, unsigned* rvRC,
                         unsigned* rowStep, unsigned* colStep,
                         hipStream_t s){
  dim3 gs(N/256, NCHUNK);
  dim3 gg(N/64, N/64);
  // ---- s-block 0 ----
  colstats_partial<float><<<gs,256,0,s>>>(x, part);
  colstats_final<<<N/256,256,0,s>>>(part, g1, be1, stA, stC);
  bnrelu_col<float,T><<<N,256,0,s>>>(x, stA, stC, buf0);
  gemm64<float,T,T,false,true><<<gg,256,0,s>>>(W1, buf0, bi1, buf1);            // Z
  rowstats<T><<<N,256,0,s>>>(buf1, g2, be2, stA, stC);
  bnrelu_row<T,T><<<N,256,0,s>>>(buf1, stA, stC, buf0);                          // C
  gemm64<T,float,T,true,false><<<gg,256,0,s>>>(buf0, W2, bi2, buf1);             // O1
  // ---- s-block 1 ----
  colstats_partial<T><<<gs,256,0,s>>>(buf1, part);
  colstats_final<<<N/256,256,0,s>>>(part, g1+N, be1+N, stA, stC);
  bnrelu_col<T,T><<<N,256,0,s>>>(buf1, stA, stC, buf0);
  gemm64<float,T,T,false,true><<<gg,256,0,s>>>(W1+(size_t)N*N, buf0, bi1+N, buf1); // Z'
  rowstats<T><<<N,256,0,s>>>(buf1, g2+N, be2+N, stA, stC);
  bnrelu_row<T,T><<<N,256,0,s>>>(buf1, stA, stC, buf0);                          // C'
  gemm64<T,float,T,true,false><<<gg,256,0,s>>>(buf0, W2+(size_t)N*N, bi2+N, buf1); // O2
  // ---- greedy mask + softmax ----
  rowmax_init2<T><<<N,256,0,s>>>(buf1, rvK, rvRC);
  greedy2<T><<<1,1024,0,s>>>(buf1, rvK, rvRC, rowStep, colStep);
  masked_softmax<T><<<N,256,0,s>>>(buf1, rowStep, colStep, out);
}

extern "C" void kernel_launch(void* const* d_in, const int* in_sizes, int n_in,
                              void* d_out, int out_size, void* d_ws, size_t ws_size,
                              hipStream_t stream){
  if (n_in < 9) return;
  const float* x   = (const float*)d_in[0];
  const float* g1  = (const float*)d_in[1];
  const float* be1 = (const float*)d_in[2];
  const float* W1  = (const float*)d_in[3];
  const float* bi1 = (const float*)d_in[4];
  const float* g2  = (const float*)d_in[5];
  const float* be2 = (const float*)d_in[6];
  const float* W2  = (const float*)d_in[7];
  const float* bi2 = (const float*)d_in[8];
  float* out = (float*)d_out;

  char* base = (char*)d_ws;
  size_t off = 0;
  auto carve = [&](size_t bytes)->void*{
    void* q = base + off;
    off = (off + bytes + 255) & ~(size_t)255;
    return q;
  };
  double*   part    = (double*)carve((size_t)NCHUNK * N * 2 * sizeof(double));
  double*   stA     = (double*)carve(N * sizeof(double));
  double*   stC     = (double*)carve(N * sizeof(double));
  u64*      rvK     = (u64*)carve(N * sizeof(u64));
  unsigned* rvRC    = (unsigned*)carve(N * sizeof(unsigned));
  unsigned* rowStep = (unsigned*)carve(N * sizeof(unsigned));
  unsigned* colStep = (unsigned*)carve(N * sizeof(unsigned));
  size_t smallEnd = off;

  const size_t matD = (size_t)N * N * sizeof(double);
  const size_t matF = (size_t)N * N * sizeof(float);
  size_t needD  = smallEnd + 2 * (matD + 256);
  size_t needF  = smallEnd + 2 * (matF + 256);
  size_t needF1 = smallEnd + 1 * (matF + 256);

  if (ws_size >= needD){
    double* b0 = (double*)carve(matD);
    double* b1 = (double*)carve(matD);
    run_pipeline<double>(x,g1,be1,W1,bi1,g2,be2,W2,bi2, out, b0, b1,
                         part, stA, stC, rvK, rvRC, rowStep, colStep, stream);
  } else if (ws_size >= needF){
    float* b0 = (float*)carve(matF);
    float* b1 = (float*)carve(matF);
    run_pipeline<float>(x,g1,be1,W1,bi1,g2,be2,W2,bi2, out, b0, b1,
                        part, stA, stC, rvK, rvRC, rowStep, colStep, stream);
  } else if (ws_size >= needF1){
    float* b0 = (float*)carve(matF);
    float* b1 = out;   // use d_out as second buffer; softmax stages rows in LDS, in-place safe
    run_pipeline<float>(x,g1,be1,W1,bi1,g2,be2,W2,bi2, out, b0, b1,
                        part, stA, stC, rvK, rvRC, rowStep, colStep, stream);
  }
}

// Round 3
// 7664.308 us; speedup vs baseline: 3.5824x; 1.5532x over previous
//
#include <hip/hip_runtime.h>
#include <math.h>

#define NEG_INF (-__builtin_inf())

typedef unsigned long long u64;

constexpr int N = 2048;
constexpr int NCHUNK = 32;
constexpr int RPC = N / NCHUNK;   // 64 rows per chunk

// ---------------- monotonic order-preserving keys ----------------
template<typename T> struct Key;
template<> struct Key<float>{
  static __device__ inline u64 pack(float x){
    unsigned u = __float_as_uint(x);
    u = (u & 0x80000000u) ? ~u : (u | 0x80000000u);
    return (u64)u;
  }
};
template<> struct Key<double>{
  static __device__ inline u64 pack(double x){
    u64 u = (u64)__double_as_longlong(x);
    return (u >> 63) ? ~u : (u | 0x8000000000000000ull);
  }
};

// comparator: bigger key wins; tie -> smaller rc
__device__ inline bool kbetter(u64 k, unsigned rc, u64 bk, unsigned brc){
  return (k > bk) || (k == bk && rc < brc);
}

// ---------------- column stats (BN1: stats over rows, per column) ----------------
template<typename T>
__global__ __launch_bounds__(256) void colstats_partial(const T* __restrict__ X, double* __restrict__ part){
  int col = blockIdx.x * 256 + threadIdx.x;
  int r0  = blockIdx.y * RPC;
  double s = 0.0, q = 0.0;
  for (int r = r0; r < r0 + RPC; ++r){
    double v = (double)X[(size_t)r * N + col];
    s += v; q += v * v;
  }
  size_t o = (size_t)blockIdx.y * N + col;
  part[o*2+0] = s; part[o*2+1] = q;
}

__global__ __launch_bounds__(256) void colstats_final(const double* __restrict__ part,
    const float* __restrict__ g, const float* __restrict__ be,
    double* __restrict__ A, double* __restrict__ C){
  int col = blockIdx.x * 256 + threadIdx.x;
  double s = 0.0, q = 0.0;
  for (int k = 0; k < NCHUNK; ++k){
    size_t o = (size_t)k * N + col;
    s += part[o*2+0]; q += part[o*2+1];
  }
  double mu  = s / (double)N;
  double var = q / (double)N - mu * mu;
  double inv = 1.0 / sqrt(var + 1e-5);
  double a = (double)g[col] * inv;
  A[col] = a;
  C[col] = (double)be[col] - mu * a;
}

// ---------------- row stats (BN2: stats per row) ----------------
template<typename T>
__global__ __launch_bounds__(256) void rowstats(const T* __restrict__ Z,
    const float* __restrict__ g, const float* __restrict__ be,
    double* __restrict__ A, double* __restrict__ C){
  __shared__ double s1[256], s2[256];
  int r = blockIdx.x, tx = threadIdx.x;
  double s = 0.0, q = 0.0;
  for (int j = tx; j < N; j += 256){
    double v = (double)Z[(size_t)r * N + j];
    s += v; q += v * v;
  }
  s1[tx] = s; s2[tx] = q; __syncthreads();
  for (int st = 128; st; st >>= 1){
    if (tx < st){ s1[tx] += s1[tx + st]; s2[tx] += s2[tx + st]; }
    __syncthreads();
  }
  if (tx == 0){
    double mu  = s1[0] / (double)N;
    double var = s2[0] / (double)N - mu * mu;
    double inv = 1.0 / sqrt(var + 1e-5);
    double a = (double)g[r] * inv;
    A[r] = a;
    C[r] = (double)be[r] - mu * a;
  }
}

// ---------------- fused BN + ReLU ----------------
template<typename Tin, typename Tout>
__global__ __launch_bounds__(256) void bnrelu_col(const Tin* __restrict__ X,
    const double* __restrict__ A, const double* __restrict__ C, Tout* __restrict__ O){
  int i = blockIdx.x;
  for (int j = threadIdx.x; j < N; j += 256){
    double v = fma((double)X[(size_t)i * N + j], A[j], C[j]);
    O[(size_t)i * N + j] = (Tout)(v > 0.0 ? v : 0.0);
  }
}

template<typename Tin, typename Tout>
__global__ __launch_bounds__(256) void bnrelu_row(const Tin* __restrict__ Z,
    const double* __restrict__ A, const double* __restrict__ C, Tout* __restrict__ O){
  int i = blockIdx.x;
  double a = A[i], c = C[i];
  for (int j = threadIdx.x; j < N; j += 256){
    double v = fma((double)Z[(size_t)i * N + j], a, c);
    O[(size_t)i * N + j] = (Tout)(v > 0.0 ? v : 0.0);
  }
}

// ---------------- f64-accumulate tiled GEMM ----------------
template<typename TA, typename TB, typename TO, bool BT, bool BIAS_ROW>
__global__ __launch_bounds__(256) void gemm64(const TA* __restrict__ A, const TB* __restrict__ B,
    const float* __restrict__ bias, TO* __restrict__ O){
  __shared__ double sA[16][68];
  __shared__ double sB[16][68];
  const int tid = threadIdx.x;
  const int tx = tid & 15, ty = tid >> 4;
  const int i0 = blockIdx.y * 64, j0 = blockIdx.x * 64;
  double acc[4][4] = {};
  for (int k0 = 0; k0 < N; k0 += 16){
    {
      int r = tid >> 2, c4 = (tid & 3) * 4;
      const TA* p = A + (size_t)(i0 + r) * N + k0 + c4;
      double v0 = (double)p[0], v1 = (double)p[1], v2 = (double)p[2], v3 = (double)p[3];
      sA[c4+0][r] = v0; sA[c4+1][r] = v1; sA[c4+2][r] = v2; sA[c4+3][r] = v3;
    }
    if (!BT){
      int k = tid >> 4, j4 = (tid & 15) * 4;
      const TB* p = B + (size_t)(k0 + k) * N + j0 + j4;
      sB[k][j4+0] = (double)p[0]; sB[k][j4+1] = (double)p[1];
      sB[k][j4+2] = (double)p[2]; sB[k][j4+3] = (double)p[3];
    } else {
      int j = tid >> 2, c4 = (tid & 3) * 4;
      const TB* p = B + (size_t)(j0 + j) * N + k0 + c4;
      double v0 = (double)p[0], v1 = (double)p[1], v2 = (double)p[2], v3 = (double)p[3];
      sB[c4+0][j] = v0; sB[c4+1][j] = v1; sB[c4+2][j] = v2; sB[c4+3][j] = v3;
    }
    __syncthreads();
    #pragma unroll
    for (int kk = 0; kk < 16; ++kk){
      double a_[4], b_[4];
      #pragma unroll
      for (int q = 0; q < 4; ++q){ a_[q] = sA[kk][ty*4+q]; b_[q] = sB[kk][tx*4+q]; }
      #pragma unroll
      for (int mi = 0; mi < 4; ++mi)
        #pragma unroll
        for (int ni = 0; ni < 4; ++ni)
          acc[mi][ni] = fma(a_[mi], b_[ni], acc[mi][ni]);
    }
    __syncthreads();
  }
  #pragma unroll
  for (int mi = 0; mi < 4; ++mi){
    int i = i0 + ty*4 + mi;
    #pragma unroll
    for (int ni = 0; ni < 4; ++ni){
      int j = j0 + tx*4 + ni;
      double bv = BIAS_ROW ? (double)bias[i] : (double)bias[j];
      O[(size_t)i * N + j] = (TO)(acc[mi][ni] + bv);
    }
  }
}

// ---------------- per-row max init (packed keys) ----------------
template<typename T>
__global__ __launch_bounds__(256) void rowmax_init2(const T* __restrict__ O,
    u64* __restrict__ rvK_g, unsigned* __restrict__ rvRC_g){
  __shared__ u64 sk[256];
  __shared__ unsigned sc[256];
  int r = blockIdx.x, tx = threadIdx.x;
  u64 bk = 0; unsigned bc = 0xFFFFFFFFu;
  for (int c = tx; c < N; c += 256){
    u64 k = Key<T>::pack(O[(size_t)r * N + c]);
    if (k > bk){ bk = k; bc = (unsigned)c; }
  }
  sk[tx] = bk; sc[tx] = bc; __syncthreads();
  for (int st = 128; st; st >>= 1){
    if (tx < st){
      if (kbetter(sk[tx+st], sc[tx+st], sk[tx], sc[tx])){ sk[tx] = sk[tx+st]; sc[tx] = sc[tx+st]; }
    }
    __syncthreads();
  }
  if (tx == 0){ rvK_g[r] = sk[0]; rvRC_g[r] = ((unsigned)r << 11) | sc[0]; }
}

// ---------------- batched greedy (v3): sort cached maxima, commit distinct-col prefix ----------------
// Exactness: with eager per-row maxima, the descending-sorted (val, rc) prefix with
// pairwise-distinct columns equals the greedy selection sequence; stop at first
// duplicate column (any prefix cut stays exact). ~2*sqrt(N) serial rounds.
template<typename T>
__global__ __launch_bounds__(1024) void greedy3(const T* __restrict__ O,
    const u64* __restrict__ rvK_g, const unsigned* __restrict__ rvRC_g,
    unsigned* __restrict__ rowStep_g, unsigned* __restrict__ colStep_g){
  __shared__ u64 rvK[N];            // cached per-row max key (0 = row dead)
  __shared__ unsigned rvRC[N];      // (row<<11)|col of cached max
  __shared__ u64 sk[N];             // sort keys = ~rvK (ascending sort => val desc)
  __shared__ unsigned src[N];       // sort rc payload
  __shared__ unsigned scratch[N];   // firstOcc (by col) in select phase; stale list in rescan phase
  __shared__ unsigned cm32[N/32];   // column-alive bitmask
  __shared__ unsigned sCompactCnt, sCnt, sL;
  const int tid  = threadIdx.x;
  const int lane = tid & 63, wave = tid >> 6;
  const unsigned BIG = 0xFFFFFFFFu;

  for (int i = tid; i < N; i += 1024){ rvK[i] = rvK_g[i]; rvRC[i] = rvRC_g[i]; }
  if (tid < N/32) cm32[tid] = 0xFFFFFFFFu;
  __syncthreads();

  unsigned t = 0;
  while (t < N){
    const unsigned alive = N - t;
    unsigned S = 1; while (S < alive) S <<= 1;

    // --- A: reset scalars ---
    if (tid == 0){ sCompactCnt = 0; sCnt = 0; sL = BIG; }
    __syncthreads();

    // --- B+C: compact alive entries to front; pad rest ---
    {
      u64 k0 = rvK[tid];
      if (k0){ unsigned p = atomicAdd(&sCompactCnt, 1u); sk[p] = ~k0; src[p] = rvRC[tid]; }
      u64 k1 = rvK[tid + 1024];
      if (k1){ unsigned p = atomicAdd(&sCompactCnt, 1u); sk[p] = ~k1; src[p] = rvRC[tid + 1024]; }
      for (unsigned p = alive + tid; p < S; p += 1024){ sk[p] = ~0ull; src[p] = BIG; }
    }
    __syncthreads();

    // --- D: bitonic sort ascending on (sk, src)  => value desc, rc asc ---
    for (unsigned k2 = 2; k2 <= S; k2 <<= 1){
      for (unsigned jj = k2 >> 1; jj > 0; jj >>= 1){
        for (unsigned p = tid; p < (S >> 1); p += 1024){
          unsigned i = ((p & ~(jj - 1)) << 1) | (p & (jj - 1));
          unsigned l = i | jj;
          bool up = ((i & k2) == 0);
          u64 ki = sk[i], kl = sk[l];
          unsigned ri = src[i], rl = src[l];
          bool swLI = (kl < ki) || (kl == ki && rl < ri);   // e[l] < e[i]
          bool swIL = (ki < kl) || (ki == kl && ri < rl);   // e[i] < e[l]
          if (up ? swLI : swIL){ sk[i] = kl; sk[l] = ki; src[i] = rl; src[l] = ri; }
        }
        __syncthreads();
      }
    }

    // --- E: first occurrence position per column ---
    for (unsigned c = tid; c < N; c += 1024) scratch[c] = BIG;
    __syncthreads();
    for (unsigned p = tid; p < alive; p += 1024) atomicMin(&scratch[src[p] & 2047u], p);
    __syncthreads();

    // --- F: L = min position whose column already appeared earlier ---
    {
      unsigned local = BIG;
      for (unsigned p = tid; p < alive; p += 1024)
        if (scratch[src[p] & 2047u] < p && p < local) local = p;
      #pragma unroll
      for (int off = 32; off; off >>= 1){
        unsigned o = __shfl_xor(local, off);
        if (o < local) local = o;
      }
      if (lane == 0 && local != BIG) atomicMin(&sL, local);
    }
    __syncthreads();
    const unsigned L = (sL < alive) ? sL : alive;   // commit prefix [0, L)

    // --- G: parallel commit ---
    for (unsigned i = tid; i < L; i += 1024){
      unsigned rc = src[i];
      unsigned r = rc >> 11, c = rc & 2047u;
      rowStep_g[r] = t + i;
      colStep_g[c] = t + i;
      rvK[r] = 0;
      atomicAnd(&cm32[c >> 5], ~(1u << (c & 31)));
    }
    __syncthreads();
    t += L;
    if (t >= N) break;

    // --- H: stale detect (cached col no longer alive) ---
    {
      u64 k0 = rvK[tid];
      if (k0){ unsigned c = rvRC[tid] & 2047u;
        if (!((cm32[c >> 5] >> (c & 31)) & 1u)) scratch[atomicAdd(&sCnt, 1u)] = (unsigned)tid; }
      u64 k1 = rvK[tid + 1024];
      if (k1){ unsigned c = rvRC[tid + 1024] & 2047u;
        if (!((cm32[c >> 5] >> (c & 31)) & 1u)) scratch[atomicAdd(&sCnt, 1u)] = (unsigned)(tid + 1024); }
    }
    __syncthreads();

    // --- I: rescan stale rows, one wave per row, branch-free ---
    {
      const unsigned cnt = sCnt;
      for (unsigned q = (unsigned)wave; q < cnt; q += 16){
        unsigned rr = scratch[q];
        const T* __restrict__ row = O + (size_t)rr * N;
        u64 bk = 0; unsigned bc = BIG;
        #pragma unroll
        for (int it = 0; it < N/64; ++it){
          int cc = lane + it * 64;
          T x = row[cc];
          u64 kk = Key<T>::pack(x);
          if (!((cm32[cc >> 5] >> (cc & 31)) & 1u)) kk = 0;
          if (kbetter(kk, (unsigned)cc, bk, bc)){ bk = kk; bc = (unsigned)cc; }
        }
        #pragma unroll
        for (int off = 32; off; off >>= 1){
          u64 ok = __shfl_xor(bk, off);
          unsigned oc = __shfl_xor(bc, off);
          if (kbetter(ok, oc, bk, bc)){ bk = ok; bc = oc; }
        }
        if (lane == 0){ rvK[rr] = bk; rvRC[rr] = (rr << 11) | (bc & 2047u); }
      }
    }
    __syncthreads();
  }
}

// ---------------- masked row softmax: keep where colStep[c] >= rowStep[r] ----------------
template<typename T>
__global__ __launch_bounds__(256) void masked_softmax(const T* __restrict__ O,
    const unsigned* __restrict__ rowStep, const unsigned* __restrict__ colStep,
    float* __restrict__ out){
  __shared__ double vals[N];
  __shared__ double red[256];
  int r = blockIdx.x, tx = threadIdx.x;
  unsigned s = rowStep[r];
  double mx = NEG_INF;
  for (int c = tx; c < N; c += 256){
    double v = (colStep[c] >= s) ? (double)O[(size_t)r * N + c] : NEG_INF;
    vals[c] = v;
    if (v > mx) mx = v;
  }
  red[tx] = mx; __syncthreads();
  for (int st = 128; st; st >>= 1){
    if (tx < st) red[tx] = fmax(red[tx], red[tx + st]);
    __syncthreads();
  }
  mx = red[0]; __syncthreads();
  double sm = 0.0;
  for (int c = tx; c < N; c += 256){
    double v = vals[c];
    if (v != NEG_INF) sm += exp(v - mx);
  }
  red[tx] = sm; __syncthreads();
  for (int st = 128; st; st >>= 1){
    if (tx < st) red[tx] += red[tx + st];
    __syncthreads();
  }
  double inv = 1.0 / red[0];
  for (int c = tx; c < N; c += 256){
    double v = vals[c];
    out[(size_t)r * N + c] = (v != NEG_INF) ? (float)(exp(v - mx) * inv) : 0.0f;
  }
}

// ---------------- pipeline ----------------
template<typename T>
static void run_pipeline(const float* x, const float* g1, const float* be1,
                         const float* W1, const float* bi1,
                         const float* g2, const float* be2,
                         const float* W2, const float* bi2,
                         float* out, T* buf0, T* buf1,
                         double* part, double* stA, double* stC,
                         u64* rvK, unsigned* rvRC,
                         unsigned* rowStep, unsigned* colStep,
                         hipStream_t s){
  dim3 gs(N/256, NCHUNK);
  dim3 gg(N/64, N/64);
  // ---- s-block 0 ----
  colstats_partial<float><<<gs,256,0,s>>>(x, part);
  colstats_final<<<N/256,256,0,s>>>(part, g1, be1, stA, stC);
  bnrelu_col<float,T><<<N,256,0,s>>>(x, stA, stC, buf0);
  gemm64<float,T,T,false,true><<<gg,256,0,s>>>(W1, buf0, bi1, buf1);            // Z
  rowstats<T><<<N,256,0,s>>>(buf1, g2, be2, stA, stC);
  bnrelu_row<T,T><<<N,256,0,s>>>(buf1, stA, stC, buf0);                          // C
  gemm64<T,float,T,true,false><<<gg,256,0,s>>>(buf0, W2, bi2, buf1);             // O1
  // ---- s-block 1 ----
  colstats_partial<T><<<gs,256,0,s>>>(buf1, part);
  colstats_final<<<N/256,256,0,s>>>(part, g1+N, be1+N, stA, stC);
  bnrelu_col<T,T><<<N,256,0,s>>>(buf1, stA, stC, buf0);
  gemm64<float,T,T,false,true><<<gg,256,0,s>>>(W1+(size_t)N*N, buf0, bi1+N, buf1); // Z'
  rowstats<T><<<N,256,0,s>>>(buf1, g2+N, be2+N, stA, stC);
  bnrelu_row<T,T><<<N,256,0,s>>>(buf1, stA, stC, buf0);                          // C'
  gemm64<T,float,T,true,false><<<gg,256,0,s>>>(buf0, W2+(size_t)N*N, bi2+N, buf1); // O2
  // ---- greedy mask + softmax ----
  rowmax_init2<T><<<N,256,0,s>>>(buf1, rvK, rvRC);
  greedy3<T><<<1,1024,0,s>>>(buf1, rvK, rvRC, rowStep, colStep);
  masked_softmax<T><<<N,256,0,s>>>(buf1, rowStep, colStep, out);
}

extern "C" void kernel_launch(void* const* d_in, const int* in_sizes, int n_in,
                              void* d_out, int out_size, void* d_ws, size_t ws_size,
                              hipStream_t stream){
  if (n_in < 9) return;
  const float* x   = (const float*)d_in[0];
  const float* g1  = (const float*)d_in[1];
  const float* be1 = (const float*)d_in[2];
  const float* W1  = (const float*)d_in[3];
  const float* bi1 = (const float*)d_in[4];
  const float* g2  = (const float*)d_in[5];
  const float* be2 = (const float*)d_in[6];
  const float* W2  = (const float*)d_in[7];
  const float* bi2 = (const float*)d_in[8];
  float* out = (float*)d_out;

  char* base = (char*)d_ws;
  size_t off = 0;
  auto carve = [&](size_t bytes)->void*{
    void* q = base + off;
    off = (off + bytes + 255) & ~(size_t)255;
    return q;
  };
  double*   part    = (double*)carve((size_t)NCHUNK * N * 2 * sizeof(double));
  double*   stA     = (double*)carve(N * sizeof(double));
  double*   stC     = (double*)carve(N * sizeof(double));
  u64*      rvK     = (u64*)carve(N * sizeof(u64));
  unsigned* rvRC    = (unsigned*)carve(N * sizeof(unsigned));
  unsigned* rowStep = (unsigned*)carve(N * sizeof(unsigned));
  unsigned* colStep = (unsigned*)carve(N * sizeof(unsigned));
  size_t smallEnd = off;

  const size_t matD = (size_t)N * N * sizeof(double);
  const size_t matF = (size_t)N * N * sizeof(float);
  size_t needD  = smallEnd + 2 * (matD + 256);
  size_t needF  = smallEnd + 2 * (matF + 256);
  size_t needF1 = smallEnd + 1 * (matF + 256);

  if (ws_size >= needD){
    double* b0 = (double*)carve(matD);
    double* b1 = (double*)carve(matD);
    run_pipeline<double>(x,g1,be1,W1,bi1,g2,be2,W2,bi2, out, b0, b1,
                         part, stA, stC, rvK, rvRC, rowStep, colStep, stream);
  } else if (ws_size >= needF){
    float* b0 = (float*)carve(matF);
    float* b1 = (float*)carve(matF);
    run_pipeline<float>(x,g1,be1,W1,bi1,g2,be2,W2,bi2, out, b0, b1,
                        part, stA, stC, rvK, rvRC, rowStep, colStep, stream);
  } else if (ws_size >= needF1){
    float* b0 = (float*)carve(matF);
    float* b1 = out;
    run_pipeline<float>(x,g1,be1,W1,bi1,g2,be2,W2,bi2, out, b0, b1,
                        part, stA, stC, rvK, rvRC, rowStep, colStep, stream);
  }
}

// Round 4
// 6818.211 us; speedup vs baseline: 4.0270x; 1.1241x over previous
//
#include <hip/hip_runtime.h>
#include <math.h>

#define NEG_INF (-__builtin_inf())

typedef unsigned long long u64;

constexpr int N = 2048;
constexpr int NCHUNK = 32;
constexpr int RPC = N / NCHUNK;   // 64 rows per chunk
constexpr int CMAX = 256;         // max candidates per round
constexpr int CTGT = 96;          // target candidates per round

// ---------------- monotonic order-preserving keys ----------------
template<typename T> struct Key;
template<> struct Key<float>{
  static __device__ inline u64 pack(float x){
    unsigned u = __float_as_uint(x);
    u = (u & 0x80000000u) ? ~u : (u | 0x80000000u);
    return (u64)u;
  }
};
template<> struct Key<double>{
  static __device__ inline u64 pack(double x){
    u64 u = (u64)__double_as_longlong(x);
    return (u >> 63) ? ~u : (u | 0x8000000000000000ull);
  }
};

// comparator: bigger key wins; tie -> smaller rc
__device__ inline bool kbetter(u64 k, unsigned rc, u64 bk, unsigned brc){
  return (k > bk) || (k == bk && rc < brc);
}

// ---------------- column stats (BN1: stats over rows, per column) ----------------
template<typename T>
__global__ __launch_bounds__(256) void colstats_partial(const T* __restrict__ X, double* __restrict__ part){
  int col = blockIdx.x * 256 + threadIdx.x;
  int r0  = blockIdx.y * RPC;
  double s = 0.0, q = 0.0;
  for (int r = r0; r < r0 + RPC; ++r){
    double v = (double)X[(size_t)r * N + col];
    s += v; q += v * v;
  }
  size_t o = (size_t)blockIdx.y * N + col;
  part[o*2+0] = s; part[o*2+1] = q;
}

__global__ __launch_bounds__(256) void colstats_final(const double* __restrict__ part,
    const float* __restrict__ g, const float* __restrict__ be,
    double* __restrict__ A, double* __restrict__ C){
  int col = blockIdx.x * 256 + threadIdx.x;
  double s = 0.0, q = 0.0;
  for (int k = 0; k < NCHUNK; ++k){
    size_t o = (size_t)k * N + col;
    s += part[o*2+0]; q += part[o*2+1];
  }
  double mu  = s / (double)N;
  double var = q / (double)N - mu * mu;
  double inv = 1.0 / sqrt(var + 1e-5);
  double a = (double)g[col] * inv;
  A[col] = a;
  C[col] = (double)be[col] - mu * a;
}

// ---------------- row stats (BN2: stats per row) ----------------
template<typename T>
__global__ __launch_bounds__(256) void rowstats(const T* __restrict__ Z,
    const float* __restrict__ g, const float* __restrict__ be,
    double* __restrict__ A, double* __restrict__ C){
  __shared__ double s1[256], s2[256];
  int r = blockIdx.x, tx = threadIdx.x;
  double s = 0.0, q = 0.0;
  for (int j = tx; j < N; j += 256){
    double v = (double)Z[(size_t)r * N + j];
    s += v; q += v * v;
  }
  s1[tx] = s; s2[tx] = q; __syncthreads();
  for (int st = 128; st; st >>= 1){
    if (tx < st){ s1[tx] += s1[tx + st]; s2[tx] += s2[tx + st]; }
    __syncthreads();
  }
  if (tx == 0){
    double mu  = s1[0] / (double)N;
    double var = s2[0] / (double)N - mu * mu;
    double inv = 1.0 / sqrt(var + 1e-5);
    double a = (double)g[r] * inv;
    A[r] = a;
    C[r] = (double)be[r] - mu * a;
  }
}

// ---------------- fused BN + ReLU ----------------
template<typename Tin, typename Tout>
__global__ __launch_bounds__(256) void bnrelu_col(const Tin* __restrict__ X,
    const double* __restrict__ A, const double* __restrict__ C, Tout* __restrict__ O){
  int i = blockIdx.x;
  for (int j = threadIdx.x; j < N; j += 256){
    double v = fma((double)X[(size_t)i * N + j], A[j], C[j]);
    O[(size_t)i * N + j] = (Tout)(v > 0.0 ? v : 0.0);
  }
}

template<typename Tin, typename Tout>
__global__ __launch_bounds__(256) void bnrelu_row(const Tin* __restrict__ Z,
    const double* __restrict__ A, const double* __restrict__ C, Tout* __restrict__ O){
  int i = blockIdx.x;
  double a = A[i], c = C[i];
  for (int j = threadIdx.x; j < N; j += 256){
    double v = fma((double)Z[(size_t)i * N + j], a, c);
    O[(size_t)i * N + j] = (Tout)(v > 0.0 ? v : 0.0);
  }
}

// ---------------- f64-accumulate tiled GEMM ----------------
template<typename TA, typename TB, typename TO, bool BT, bool BIAS_ROW>
__global__ __launch_bounds__(256) void gemm64(const TA* __restrict__ A, const TB* __restrict__ B,
    const float* __restrict__ bias, TO* __restrict__ O){
  __shared__ double sA[16][68];
  __shared__ double sB[16][68];
  const int tid = threadIdx.x;
  const int tx = tid & 15, ty = tid >> 4;
  const int i0 = blockIdx.y * 64, j0 = blockIdx.x * 64;
  double acc[4][4] = {};
  for (int k0 = 0; k0 < N; k0 += 16){
    {
      int r = tid >> 2, c4 = (tid & 3) * 4;
      const TA* p = A + (size_t)(i0 + r) * N + k0 + c4;
      double v0 = (double)p[0], v1 = (double)p[1], v2 = (double)p[2], v3 = (double)p[3];
      sA[c4+0][r] = v0; sA[c4+1][r] = v1; sA[c4+2][r] = v2; sA[c4+3][r] = v3;
    }
    if (!BT){
      int k = tid >> 4, j4 = (tid & 15) * 4;
      const TB* p = B + (size_t)(k0 + k) * N + j0 + j4;
      sB[k][j4+0] = (double)p[0]; sB[k][j4+1] = (double)p[1];
      sB[k][j4+2] = (double)p[2]; sB[k][j4+3] = (double)p[3];
    } else {
      int j = tid >> 2, c4 = (tid & 3) * 4;
      const TB* p = B + (size_t)(j0 + j) * N + k0 + c4;
      double v0 = (double)p[0], v1 = (double)p[1], v2 = (double)p[2], v3 = (double)p[3];
      sB[c4+0][j] = v0; sB[c4+1][j] = v1; sB[c4+2][j] = v2; sB[c4+3][j] = v3;
    }
    __syncthreads();
    #pragma unroll
    for (int kk = 0; kk < 16; ++kk){
      double a_[4], b_[4];
      #pragma unroll
      for (int q = 0; q < 4; ++q){ a_[q] = sA[kk][ty*4+q]; b_[q] = sB[kk][tx*4+q]; }
      #pragma unroll
      for (int mi = 0; mi < 4; ++mi)
        #pragma unroll
        for (int ni = 0; ni < 4; ++ni)
          acc[mi][ni] = fma(a_[mi], b_[ni], acc[mi][ni]);
    }
    __syncthreads();
  }
  #pragma unroll
  for (int mi = 0; mi < 4; ++mi){
    int i = i0 + ty*4 + mi;
    #pragma unroll
    for (int ni = 0; ni < 4; ++ni){
      int j = j0 + tx*4 + ni;
      double bv = BIAS_ROW ? (double)bias[i] : (double)bias[j];
      O[(size_t)i * N + j] = (TO)(acc[mi][ni] + bv);
    }
  }
}

// ---------------- per-row max init (packed keys) ----------------
template<typename T>
__global__ __launch_bounds__(256) void rowmax_init2(const T* __restrict__ O,
    u64* __restrict__ rvK_g, unsigned* __restrict__ rvRC_g){
  __shared__ u64 sk[256];
  __shared__ unsigned sc[256];
  int r = blockIdx.x, tx = threadIdx.x;
  u64 bk = 0; unsigned bc = 0xFFFFFFFFu;
  for (int c = tx; c < N; c += 256){
    u64 k = Key<T>::pack(O[(size_t)r * N + c]);
    if (k > bk){ bk = k; bc = (unsigned)c; }
  }
  sk[tx] = bk; sc[tx] = bc; __syncthreads();
  for (int st = 128; st; st >>= 1){
    if (tx < st){
      if (kbetter(sk[tx+st], sc[tx+st], sk[tx], sc[tx])){ sk[tx] = sk[tx+st]; sc[tx] = sc[tx+st]; }
    }
    __syncthreads();
  }
  if (tx == 0){ rvK_g[r] = sk[0]; rvRC_g[r] = ((unsigned)r << 11) | sc[0]; }
}

// ---------------- batched greedy v4: radix-select top-C, sort C, commit prefix ----------------
template<typename T>
__global__ __launch_bounds__(1024) void greedy4(const T* __restrict__ O,
    const u64* __restrict__ rvK_g, const unsigned* __restrict__ rvRC_g,
    unsigned* __restrict__ rowStep_g, unsigned* __restrict__ colStep_g){
  __shared__ u64 rvK[N];
  __shared__ unsigned rvRC[N];
  __shared__ unsigned cm32[N/32];
  __shared__ unsigned hist[16][256];     // per-wave sub-histograms
  __shared__ unsigned hsum[256];
  __shared__ u64 candK[CMAX];
  __shared__ unsigned candRC[CMAX];
  __shared__ unsigned foc[N];            // firstOcc per col; reused as stale-row list
  __shared__ u64 sTau;
  __shared__ unsigned sBstar, sTotal, sPre, sDone, sC, sCnt, sL;
  const int tid  = threadIdx.x;
  const int lane = tid & 63, wave = tid >> 6;
  const unsigned BIG = 0xFFFFFFFFu;
  const u64 lmask = ((u64)1 << lane) - 1;

  for (int i = tid; i < N; i += 1024){ rvK[i] = rvK_g[i]; rvRC[i] = rvRC_g[i]; }
  if (tid < N/32) cm32[tid] = 0xFFFFFFFFu;
  __syncthreads();

  unsigned t = 0;
  while (t < N){
    const unsigned alive = N - t;
    const unsigned target = (alive < CTGT) ? alive : CTGT;

    if (tid == 0){ sC = 0; sCnt = 0; sL = BIG; }

    // ===== 1. radix-select threshold tau (descending top-`target`, count <= CMAX) =====
    u64 base = 0; unsigned pre = 0; int shift = 56;
    for (int level = 0; level < 8; ++level){
      for (int i = tid; i < 16*256; i += 1024) ((unsigned*)hist)[i] = 0;
      __syncthreads();
      {
        u64 k0 = rvK[tid];
        if (k0 >= base && k0 && ((k0 - base) >> shift) < 256)
          atomicAdd(&hist[wave][(unsigned)((k0 - base) >> shift)], 1u);
        u64 k1 = rvK[tid + 1024];
        if (k1 >= base && k1 && ((k1 - base) >> shift) < 256)
          atomicAdd(&hist[wave][(unsigned)((k1 - base) >> shift)], 1u);
      }
      __syncthreads();
      if (tid < 256){
        unsigned s = 0;
        #pragma unroll
        for (int w = 0; w < 16; ++w) s += hist[w][tid];
        hsum[tid] = s;
      }
      __syncthreads();
      if (wave == 0){
        // lane covers bins [4*lane .. 4*lane+3]
        unsigned v0 = hsum[4*lane+0], v1 = hsum[4*lane+1], v2 = hsum[4*lane+2], v3 = hsum[4*lane+3];
        unsigned s3 = v3, s2 = v2+v3, s1 = v1+s2, tot = v0+s1;
        unsigned run = tot;   // inclusive suffix over lane totals
        #pragma unroll
        for (int off = 1; off < 64; off <<= 1){
          unsigned x = __shfl_down(run, off);
          if (lane + off < 64) run += x;
        }
        unsigned above = run - tot;  // strictly-higher lanes
        unsigned ge0 = tot + above, ge1 = s1 + above, ge2 = s2 + above, ge3 = s3 + above;
        int bl = -1; unsigned geb = 0, vb = 0;
        if (pre + ge3 >= target){ bl = 4*lane+3; geb = ge3; vb = v3; }
        else if (pre + ge2 >= target){ bl = 4*lane+2; geb = ge2; vb = v2; }
        else if (pre + ge1 >= target){ bl = 4*lane+1; geb = ge1; vb = v1; }
        else if (pre + ge0 >= target){ bl = 4*lane+0; geb = ge0; vb = v0; }
        int bmax = bl;
        #pragma unroll
        for (int off = 32; off; off >>= 1){
          int o = __shfl_xor(bmax, off);
          if (o > bmax) bmax = o;
        }
        if (bmax < 0){
          if (lane == 0){  // everything fits below target
            sBstar = 0; sTotal = pre + run; sPre = pre; sDone = 1;
          }
        } else if (bl == bmax){
          unsigned total = pre + geb;
          sBstar = (unsigned)bmax; sTotal = total; sPre = pre + geb - vb;
          sDone = (total <= CMAX || shift == 0) ? 1u : 0u;
        }
      }
      __syncthreads();
      unsigned bstar = sBstar;
      if (sDone){
        if (tid == 0) sTau = base + ((u64)bstar << shift);
        break;
      }
      base += ((u64)bstar << shift);
      pre = sPre;
      shift -= 8;
      __syncthreads();  // protect hist re-zero vs. laggard readers
    }
    __syncthreads();
    const u64 tau = sTau;

    // ===== 2. ballot-compact candidates (key >= tau, alive) =====
    {
      u64 k0 = rvK[tid];
      bool p0 = (k0 != 0) && (k0 >= tau);
      u64 m0 = __ballot(p0);
      unsigned b0 = 0;
      if (lane == 0) b0 = atomicAdd(&sC, (unsigned)__popcll(m0));
      b0 = __shfl(b0, 0);
      if (p0){
        unsigned pos = b0 + (unsigned)__popcll(m0 & lmask);
        if (pos < CMAX){ candK[pos] = k0; candRC[pos] = rvRC[tid]; }
      }
      u64 k1 = rvK[tid + 1024];
      bool p1 = (k1 != 0) && (k1 >= tau);
      u64 m1 = __ballot(p1);
      unsigned b1 = 0;
      if (lane == 0) b1 = atomicAdd(&sC, (unsigned)__popcll(m1));
      b1 = __shfl(b1, 0);
      if (p1){
        unsigned pos = b1 + (unsigned)__popcll(m1 & lmask);
        if (pos < CMAX){ candK[pos] = k1; candRC[pos] = rvRC[tid + 1024]; }
      }
    }
    __syncthreads();
    const unsigned C = (sC < CMAX) ? sC : CMAX;
    unsigned S = 2; while (S < C) S <<= 1;

    // pad
    for (unsigned p = C + tid; p < S; p += 1024){ candK[p] = 0; candRC[p] = BIG; }
    __syncthreads();

    // ===== 3. bitonic sort: key desc, rc asc =====
    for (unsigned k2 = 2; k2 <= S; k2 <<= 1){
      for (unsigned jj = k2 >> 1; jj > 0; jj >>= 1){
        if (tid < (S >> 1)){
          unsigned i = ((tid & ~(jj - 1)) << 1) | (tid & (jj - 1));
          unsigned l = i | jj;
          bool up = ((i & k2) == 0);
          u64 ki = candK[i], kl = candK[l];
          unsigned ri = candRC[i], rl = candRC[l];
          bool lBeforeI = (kl > ki) || (kl == ki && rl < ri);
          bool iBeforeL = (ki > kl) || (ki == kl && ri < rl);
          if (up ? lBeforeI : iBeforeL){
            candK[i] = kl; candK[l] = ki; candRC[i] = rl; candRC[l] = ri;
          }
        }
        __syncthreads();
      }
    }

    // ===== 4. first occurrence per column; L = first duplicate position =====
    if (tid < C) foc[candRC[tid] & 2047u] = BIG;
    __syncthreads();
    if (tid < C) atomicMin(&foc[candRC[tid] & 2047u], (unsigned)tid);
    __syncthreads();
    {
      unsigned loc = BIG;
      if (tid < C){
        unsigned c = candRC[tid] & 2047u;
        if (foc[c] < (unsigned)tid) loc = (unsigned)tid;
      }
      #pragma unroll
      for (int off = 32; off; off >>= 1){
        unsigned o = __shfl_xor(loc, off);
        if (o < loc) loc = o;
      }
      if (lane == 0 && loc != BIG) atomicMin(&sL, loc);
    }
    __syncthreads();
    const unsigned L = (sL < C) ? sL : C;

    // ===== 5. commit prefix [0, L) =====
    if (tid < L){
      unsigned rc = candRC[tid];
      unsigned r = rc >> 11, c = rc & 2047u;
      rowStep_g[r] = t + tid;
      colStep_g[c] = t + tid;
      rvK[r] = 0;
      atomicAnd(&cm32[c >> 5], ~(1u << (c & 31)));
    }
    __syncthreads();
    t += L;
    if (t >= N) break;

    // ===== 6. stale detect (ballot-compacted list in foc) =====
    {
      u64 k0 = rvK[tid];
      unsigned c0 = rvRC[tid] & 2047u;
      bool p0 = (k0 != 0) && !((cm32[c0 >> 5] >> (c0 & 31)) & 1u);
      u64 m0 = __ballot(p0);
      unsigned b0 = 0;
      if (lane == 0) b0 = atomicAdd(&sCnt, (unsigned)__popcll(m0));
      b0 = __shfl(b0, 0);
      if (p0) foc[b0 + (unsigned)__popcll(m0 & lmask)] = (unsigned)tid;

      u64 k1 = rvK[tid + 1024];
      unsigned c1 = rvRC[tid + 1024] & 2047u;
      bool p1 = (k1 != 0) && !((cm32[c1 >> 5] >> (c1 & 31)) & 1u);
      u64 m1 = __ballot(p1);
      unsigned b1 = 0;
      if (lane == 0) b1 = atomicAdd(&sCnt, (unsigned)__popcll(m1));
      b1 = __shfl(b1, 0);
      if (p1) foc[b1 + (unsigned)__popcll(m1 & lmask)] = (unsigned)(tid + 1024);
    }
    __syncthreads();

    // ===== 7. rescan stale rows, one wave per row, branch-free =====
    {
      const unsigned cnt = sCnt;
      for (unsigned q = (unsigned)wave; q < cnt; q += 16){
        unsigned rr = foc[q];
        const T* __restrict__ row = O + (size_t)rr * N;
        u64 bk = 0; unsigned bc = BIG;
        #pragma unroll
        for (int it = 0; it < N/64; ++it){
          int cc = lane + it * 64;
          T x = row[cc];
          u64 kk = Key<T>::pack(x);
          if (!((cm32[cc >> 5] >> (cc & 31)) & 1u)) kk = 0;
          if (kbetter(kk, (unsigned)cc, bk, bc)){ bk = kk; bc = (unsigned)cc; }
        }
        #pragma unroll
        for (int off = 32; off; off >>= 1){
          u64 ok = __shfl_xor(bk, off);
          unsigned oc = __shfl_xor(bc, off);
          if (kbetter(ok, oc, bk, bc)){ bk = ok; bc = oc; }
        }
        if (lane == 0){ rvK[rr] = bk; rvRC[rr] = (rr << 11) | (bc & 2047u); }
      }
    }
    __syncthreads();
  }
}

// ---------------- masked row softmax: keep where colStep[c] >= rowStep[r] ----------------
template<typename T>
__global__ __launch_bounds__(256) void masked_softmax(const T* __restrict__ O,
    const unsigned* __restrict__ rowStep, const unsigned* __restrict__ colStep,
    float* __restrict__ out){
  __shared__ double vals[N];
  __shared__ double red[256];
  int r = blockIdx.x, tx = threadIdx.x;
  unsigned s = rowStep[r];
  double mx = NEG_INF;
  for (int c = tx; c < N; c += 256){
    double v = (colStep[c] >= s) ? (double)O[(size_t)r * N + c] : NEG_INF;
    vals[c] = v;
    if (v > mx) mx = v;
  }
  red[tx] = mx; __syncthreads();
  for (int st = 128; st; st >>= 1){
    if (tx < st) red[tx] = fmax(red[tx], red[tx + st]);
    __syncthreads();
  }
  mx = red[0]; __syncthreads();
  double sm = 0.0;
  for (int c = tx; c < N; c += 256){
    double v = vals[c];
    if (v != NEG_INF) sm += exp(v - mx);
  }
  red[tx] = sm; __syncthreads();
  for (int st = 128; st; st >>= 1){
    if (tx < st) red[tx] += red[tx + st];
    __syncthreads();
  }
  double inv = 1.0 / red[0];
  for (int c = tx; c < N; c += 256){
    double v = vals[c];
    out[(size_t)r * N + c] = (v != NEG_INF) ? (float)(exp(v - mx) * inv) : 0.0f;
  }
}

// ---------------- pipeline ----------------
template<typename T>
static void run_pipeline(const float* x, const float* g1, const float* be1,
                         const float* W1, const float* bi1,
                         const float* g2, const float* be2,
                         const float* W2, const float* bi2,
                         float* out, T* buf0, T* buf1,
                         double* part, double* stA, double* stC,
                         u64* rvK, unsigned* rvRC,
                         unsigned* rowStep, unsigned* colStep,
                         hipStream_t s){
  dim3 gs(N/256, NCHUNK);
  dim3 gg(N/64, N/64);
  // ---- s-block 0 ----
  colstats_partial<float><<<gs,256,0,s>>>(x, part);
  colstats_final<<<N/256,256,0,s>>>(part, g1, be1, stA, stC);
  bnrelu_col<float,T><<<N,256,0,s>>>(x, stA, stC, buf0);
  gemm64<float,T,T,false,true><<<gg,256,0,s>>>(W1, buf0, bi1, buf1);            // Z
  rowstats<T><<<N,256,0,s>>>(buf1, g2, be2, stA, stC);
  bnrelu_row<T,T><<<N,256,0,s>>>(buf1, stA, stC, buf0);                          // C
  gemm64<T,float,T,true,false><<<gg,256,0,s>>>(buf0, W2, bi2, buf1);             // O1
  // ---- s-block 1 ----
  colstats_partial<T><<<gs,256,0,s>>>(buf1, part);
  colstats_final<<<N/256,256,0,s>>>(part, g1+N, be1+N, stA, stC);
  bnrelu_col<T,T><<<N,256,0,s>>>(buf1, stA, stC, buf0);
  gemm64<float,T,T,false,true><<<gg,256,0,s>>>(W1+(size_t)N*N, buf0, bi1+N, buf1); // Z'
  rowstats<T><<<N,256,0,s>>>(buf1, g2+N, be2+N, stA, stC);
  bnrelu_row<T,T><<<N,256,0,s>>>(buf1, stA, stC, buf0);                          // C'
  gemm64<T,float,T,true,false><<<gg,256,0,s>>>(buf0, W2+(size_t)N*N, bi2+N, buf1); // O2
  // ---- greedy mask + softmax ----
  rowmax_init2<T><<<N,256,0,s>>>(buf1, rvK, rvRC);
  greedy4<T><<<1,1024,0,s>>>(buf1, rvK, rvRC, rowStep, colStep);
  masked_softmax<T><<<N,256,0,s>>>(buf1, rowStep, colStep, out);
}

extern "C" void kernel_launch(void* const* d_in, const int* in_sizes, int n_in,
                              void* d_out, int out_size, void* d_ws, size_t ws_size,
                              hipStream_t stream){
  if (n_in < 9) return;
  const float* x   = (const float*)d_in[0];
  const float* g1  = (const float*)d_in[1];
  const float* be1 = (const float*)d_in[2];
  const float* W1  = (const float*)d_in[3];
  const float* bi1 = (const float*)d_in[4];
  const float* g2  = (const float*)d_in[5];
  const float* be2 = (const float*)d_in[6];
  const float* W2  = (const float*)d_in[7];
  const float* bi2 = (const float*)d_in[8];
  float* out = (float*)d_out;

  char* base = (char*)d_ws;
  size_t off = 0;
  auto carve = [&](size_t bytes)->void*{
    void* q = base + off;
    off = (off + bytes + 255) & ~(size_t)255;
    return q;
  };
  double*   part    = (double*)carve((size_t)NCHUNK * N * 2 * sizeof(double));
  double*   stA     = (double*)carve(N * sizeof(double));
  double*   stC     = (double*)carve(N * sizeof(double));
  u64*      rvK     = (u64*)carve(N * sizeof(u64));
  unsigned* rvRC    = (unsigned*)carve(N * sizeof(unsigned));
  unsigned* rowStep = (unsigned*)carve(N * sizeof(unsigned));
  unsigned* colStep = (unsigned*)carve(N * sizeof(unsigned));
  size_t smallEnd = off;

  const size_t matD = (size_t)N * N * sizeof(double);
  const size_t matF = (size_t)N * N * sizeof(float);
  size_t needD  = smallEnd + 2 * (matD + 256);
  size_t needF  = smallEnd + 2 * (matF + 256);
  size_t needF1 = smallEnd + 1 * (matF + 256);

  if (ws_size >= needD){
    double* b0 = (double*)carve(matD);
    double* b1 = (double*)carve(matD);
    run_pipeline<double>(x,g1,be1,W1,bi1,g2,be2,W2,bi2, out, b0, b1,
                         part, stA, stC, rvK, rvRC, rowStep, colStep, stream);
  } else if (ws_size >= needF){
    float* b0 = (float*)carve(matF);
    float* b1 = (float*)carve(matF);
    run_pipeline<float>(x,g1,be1,W1,bi1,g2,be2,W2,bi2, out, b0, b1,
                        part, stA, stC, rvK, rvRC, rowStep, colStep, stream);
  } else if (ws_size >= needF1){
    float* b0 = (float*)carve(matF);
    float* b1 = out;
    run_pipeline<float>(x,g1,be1,W1,bi1,g2,be2,W2,bi2, out, b0, b1,
                        part, stA, stC, rvK, rvRC, rowStep, colStep, stream);
  }
}